// Round 3
// baseline (7161.024 us; speedup 1.0000x reference)
//
#include <hip/hip_runtime.h>
#include <stdint.h>
#include <math.h>

// Problem constants
#define NN    50000       // N_NODES
#define NE    400000      // N_EDGES
#define NL    50000       // N_LINKS
#define TOT   12800000    // NN*256
#define PW1   200000ull   // words per 256-bit plane  (NN*4)
#define PW8   400000ull   // words per 512-bit plane  (NN*8)
#define PW2   100000ull   // words per 128-bit plane  (NN*2)

#define JAX_PARTITIONABLE 1

struct K8 { uint32_t a[4]; uint32_t b[4]; };

// ---------------- Threefry-2x32 (20 rounds) ----------------
__host__ __device__ inline uint32_t rotl32(uint32_t x, int r){ return (x<<r)|(x>>(32-r)); }

__host__ __device__ inline void tf2x32(uint32_t k0, uint32_t k1, uint32_t x0, uint32_t x1,
                                       uint32_t &o0, uint32_t &o1) {
  uint32_t k2 = k0 ^ k1 ^ 0x1BD11BDAu;
  x0 += k0; x1 += k1;
#define TFR(r) { x0 += x1; x1 = rotl32(x1,(r)); x1 ^= x0; }
  TFR(13) TFR(15) TFR(26) TFR(6)
  x0 += k1; x1 += k2 + 1u;
  TFR(17) TFR(29) TFR(16) TFR(24)
  x0 += k2; x1 += k0 + 2u;
  TFR(13) TFR(15) TFR(26) TFR(6)
  x0 += k0; x1 += k1 + 3u;
  TFR(17) TFR(29) TFR(16) TFR(24)
  x0 += k1; x1 += k2 + 4u;
  TFR(13) TFR(15) TFR(26) TFR(6)
  x0 += k2; x1 += k0 + 5u;
#undef TFR
  o0 = x0; o1 = x1;
}

__device__ inline float u01(uint32_t b){
  return __uint_as_float((b>>9) | 0x3f800000u) - 1.0f;   // [1,2) - 1, exact
}

__device__ inline uint32_t jax_bits32(uint32_t ka, uint32_t kb, uint32_t i, uint32_t total){
#if JAX_PARTITIONABLE
  uint32_t o0,o1; tf2x32(ka,kb, 0u, i, o0,o1); return o0^o1;
#else
  uint32_t h = total>>1; uint32_t o0,o1;
  if (i < h){ tf2x32(ka,kb, i, i+h, o0,o1); return o0; }
  else      { tf2x32(ka,kb, i-h, i, o0,o1); return o1; }
#endif
}

__device__ inline double shflxor_d(double x, int m){
  union { double d; int i[2]; } u; u.d = x;
  u.i[0] = __shfl_xor(u.i[0], m, 64);
  u.i[1] = __shfl_xor(u.i[1], m, 64);
  return u.d;
}

// exact fp32 LIF step: v = fl(fl(v*0.5)+a); d = fl(v-0.2); s=(d>=0); v = s?d:v
__device__ inline bool lif32(float &v, float a){
  v = __fadd_rn(__fmul_rn(v, 0.5f), a);
  float d = __fsub_rn(v, 0.2f);
  bool s = (d >= 0.0f);
  v = s ? d : v;
  return s;
}

// ---------------- CSR build (by dst), deterministic edge order ----------------
__global__ __launch_bounds__(256) void k_hist(const int* __restrict__ dst, int* __restrict__ cnt){
  int e = blockIdx.x*256 + threadIdx.x;
  if (e < NE) atomicAdd(&cnt[dst[e]], 1);
}

__global__ __launch_bounds__(1024) void k_scan(const int* __restrict__ cnt,
    int* __restrict__ rp, int* __restrict__ cur){
  __shared__ int buf[1024];
  __shared__ int carry;
  int tid = threadIdx.x;
  if (tid==0) carry = 0;
  __syncthreads();
  for (int base=0; base<NN; base+=1024){
    int v = (base+tid < NN) ? cnt[base+tid] : 0;
    buf[tid] = v; __syncthreads();
    for (int off=1; off<1024; off<<=1){
      int t = (tid>=off) ? buf[tid-off] : 0;
      __syncthreads();
      buf[tid] += t;
      __syncthreads();
    }
    int excl = buf[tid] - v + carry;
    if (base+tid < NN){ rp[base+tid] = excl; cur[base+tid] = excl; }
    __syncthreads();
    if (tid==0) carry += buf[1023];
    __syncthreads();
  }
  if (tid==0) rp[NN] = NE;
}

__global__ __launch_bounds__(256) void k_scatter(const int* __restrict__ dst,
    int* __restrict__ cur, int* __restrict__ eidx){
  int e = blockIdx.x*256 + threadIdx.x;
  if (e < NE){ int p = atomicAdd(&cur[dst[e]], 1); eidx[p] = e; }
}

__global__ __launch_bounds__(256) void k_sortrow(const int* __restrict__ rp,
    int* __restrict__ eidx, const int* __restrict__ esrc, const float* __restrict__ ew,
    int* __restrict__ csrc, float* __restrict__ cw){
  int n = blockIdx.x*256 + threadIdx.x;
  if (n >= NN) return;
  int lo = rp[n], hi = rp[n+1];
  for (int a=lo+1; a<hi; a++){
    int k = eidx[a]; int b = a-1;
    while (b>=lo && eidx[b]>k){ eidx[b+1]=eidx[b]; b--; }
    eidx[b+1] = k;
  }
  for (int p=lo; p<hi; p++){ int e = eidx[p]; csrc[p] = esrc[e]; cw[p] = ew[e]; }
}

// ---------------- Stage A: inp(t) = poisson(x, k1[t]) ----------------
__global__ __launch_bounds__(256) void k_pois_x(const float* __restrict__ x,
    uint64_t* __restrict__ bits, K8 K){
  uint32_t i = blockIdx.x*256u + threadIdx.x;
  float xv = x[i];
  #pragma unroll
  for (int t=0;t<4;t++){
    bool b = (u01(jax_bits32(K.a[t],K.b[t], i, TOT)) <= xv);
    uint64_t w = __ballot(b);
    if ((threadIdx.x & 63u)==0u) bits[(size_t)t*PW1 + (i>>6)] = w;
  }
}

// ---------------- Stage B: h0(t) fp32 gather (edge order) + poisson(h0,k2) ----------------
__global__ __launch_bounds__(256) void k_h0(const int* __restrict__ rp,
    const int* __restrict__ csrc, const float* __restrict__ cw,
    const uint64_t* __restrict__ inb, uint64_t* __restrict__ outb, K8 K){
  int n = blockIdx.x, f = threadIdx.x;
  int wi = f>>6, sh = f&63;
  int lo = rp[n], hi = rp[n+1];
  float a0=0.f,a1=0.f,a2=0.f,a3=0.f;
  for (int p=lo;p<hi;p++){
    int s = csrc[p]; float w = cw[p];
    const uint64_t* bp = inb + (size_t)s*4 + wi;
    a0 = __fadd_rn(a0, ((bp[0*PW1]>>sh)&1ull) ? w : 0.0f);
    a1 = __fadd_rn(a1, ((bp[1*PW1]>>sh)&1ull) ? w : 0.0f);
    a2 = __fadd_rn(a2, ((bp[2*PW1]>>sh)&1ull) ? w : 0.0f);
    a3 = __fadd_rn(a3, ((bp[3*PW1]>>sh)&1ull) ? w : 0.0f);
  }
  float acc[4] = {a0,a1,a2,a3};
  uint32_t i = (uint32_t)n*256u + (uint32_t)f;
  #pragma unroll
  for (int t=0;t<4;t++){
    bool b = (u01(jax_bits32(K.a[t],K.b[t], i, TOT)) <= acc[t]);
    uint64_t w = __ballot(b);
    if (sh==0) outb[(size_t)t*PW1 + (size_t)n*4 + wi] = w;
  }
}

// ---------------- Stage C: z0 = LIF_t(hs0 @ W1)  (K=256, M=256) ----------------
__global__ __launch_bounds__(256) void k_z0(const uint64_t* __restrict__ inb,
    const float* __restrict__ W, uint64_t* __restrict__ outb){
  int j = threadIdx.x;
  int n0 = blockIdx.x*4;
  float v[4] = {0.f,0.f,0.f,0.f};
  for (int t=0;t<4;t++){
    const uint64_t* bp = inb + (size_t)t*PW1 + (size_t)n0*4;
    #pragma unroll
    for (int i=0;i<4;i++){
      float acc = 0.0f;
      #pragma unroll
      for (int kw=0;kw<4;kw++){
        uint64_t w = bp[(size_t)i*4+kw];
        const float* Wp = W + (size_t)(kw*64)*256 + j;
        while (w){                                  // ascending k within word
          int kk = __builtin_ctzll(w); w &= w-1;
          acc = __fadd_rn(acc, Wp[(size_t)kk*256]);
        }
      }
      bool s = lif32(v[i], acc);
      uint64_t bw = __ballot(s);
      if ((j&63)==0) outb[(size_t)t*PW1 + (size_t)(n0+i)*4 + (j>>6)] = bw;
    }
  }
}

// ---------------- Stage D: h1(t) fp32 gather over concat(zs0,hs0), LIF -> hs1 ----------------
__global__ __launch_bounds__(512) void k_h1(const int* __restrict__ rp,
    const int* __restrict__ csrc, const float* __restrict__ cw,
    const uint64_t* __restrict__ zs0b, const uint64_t* __restrict__ hs0b,
    uint64_t* __restrict__ hs1b){
  int n = blockIdx.x, f = threadIdx.x;           // f in [0,512)
  int wi = f>>6, sh = f&63;
  const uint64_t* plane = (wi<4) ? zs0b : hs0b;
  int wo = (wi<4) ? wi : wi-4;
  int lo = rp[n], hi = rp[n+1];
  float a[4] = {0.f,0.f,0.f,0.f};
  for (int p=lo;p<hi;p++){
    int s = csrc[p]; float w = cw[p];
    const uint64_t* bp = plane + (size_t)s*4 + wo;
    #pragma unroll
    for (int t=0;t<4;t++)
      a[t] = __fadd_rn(a[t], ((bp[(size_t)t*PW1]>>sh)&1ull) ? w : 0.0f);
  }
  float v = 0.0f;
  #pragma unroll
  for (int t=0;t<4;t++){
    bool s = lif32(v, a[t]);
    uint64_t bw = __ballot(s);
    if (sh==0) hs1b[(size_t)t*PW8 + (size_t)n*8 + wi] = bw;
  }
}

// ---------------- Stage E: z1 = LIF_t(hs1 @ W2)  (K=512, M=128) ----------------
__global__ __launch_bounds__(128) void k_z1(const uint64_t* __restrict__ inb,
    const float* __restrict__ W, uint64_t* __restrict__ outb){
  int j = threadIdx.x;
  int n0 = blockIdx.x*4;
  float v[4] = {0.f,0.f,0.f,0.f};
  for (int t=0;t<4;t++){
    const uint64_t* bp = inb + (size_t)t*PW8 + (size_t)n0*8;
    #pragma unroll
    for (int i=0;i<4;i++){
      float acc = 0.0f;
      #pragma unroll
      for (int kw=0;kw<8;kw++){
        uint64_t w = bp[(size_t)i*8+kw];
        const float* Wp = W + (size_t)(kw*64)*128 + j;
        while (w){
          int kk = __builtin_ctzll(w); w &= w-1;
          acc = __fadd_rn(acc, Wp[(size_t)kk*128]);
        }
      }
      bool s = lif32(v[i], acc);
      uint64_t bw = __ballot(s);
      if ((j&63)==0) outb[(size_t)t*PW2 + (size_t)(n0+i)*2 + (j>>6)] = bw;
    }
  }
}

// ---------------- Stage F: decoder + y + sigmoid ----------------
// block = 128 threads: wave0 = row i (ns), wave1 = row i+L (nt)
__global__ __launch_bounds__(128) void k_dec_y(const int* __restrict__ ns,
    const int* __restrict__ nt, const uint64_t* __restrict__ zs1b,
    const float* __restrict__ Wd, const float* __restrict__ bd,
    const float* __restrict__ wrec, float* __restrict__ out){
  int i = blockIdx.x;
  int tid = threadIdx.x;
  int half = tid>>6, j = tid&63;
  int node = half ? nt[i] : ns[i];
  float bdj = bd[j];
  double wrecj = (double)wrec[j];
  __shared__ uint64_t sw[2];
  float v = 0.0f;
  double ysum = 0.0;
  for (int t=0;t<4;t++){
    uint64_t w0 = zs1b[(size_t)t*PW2 + (size_t)node*2 + 0];
    uint64_t w1 = zs1b[(size_t)t*PW2 + (size_t)node*2 + 1];
    float acc = 0.0f;                          // k-sum FIRST, bias added after
    while (w0){
      int kk = __builtin_ctzll(w0); w0 &= w0-1;
      acc = __fadd_rn(acc, Wd[(size_t)kk*64 + j]);
    }
    while (w1){
      int kk = __builtin_ctzll(w1); w1 &= w1-1;
      acc = __fadd_rn(acc, Wd[(size_t)(64+kk)*64 + j]);
    }
    acc = __fadd_rn(acc, bdj);                 // matmul result + bd (separate op)
    bool s = lif32(v, acc);
    uint64_t bw = __ballot(s);
    if (j==0) sw[half] = bw;
    __syncthreads();
    uint64_t m = sw[0] & sw[1];
    __syncthreads();
    double term = ((m>>j)&1ull) ? wrecj : 0.0;
    #pragma unroll
    for (int off=1; off<64; off<<=1) term += shflxor_d(term, off);
    ysum += term;
  }
  if (tid==0) out[i] = (float)(1.0/(1.0 + exp(-0.25*ysum)));
}

// ---------------- Launcher ----------------
extern "C" void kernel_launch(void* const* d_in, const int* in_sizes, int n_in,
                              void* d_out, int out_size, void* d_ws, size_t ws_size,
                              hipStream_t stream) {
  const float* x    = (const float*)d_in[0];
  const float* W1   = (const float*)d_in[1];
  const float* W2   = (const float*)d_in[2];
  const float* Wd   = (const float*)d_in[3];
  const float* bd   = (const float*)d_in[4];
  const float* wrec = (const float*)d_in[5];
  const float* ew   = (const float*)d_in[6];
  const int* esrc   = (const int*)d_in[7];
  const int* edst   = (const int*)d_in[8];
  const int* ns     = (const int*)d_in[9];
  const int* nt     = (const int*)d_in[10];
  float* out = (float*)d_out;
  (void)in_sizes; (void)n_in; (void)out_size; (void)ws_size;

  // workspace layout (~41 MB)
  char* p = (char*)d_ws;
  uint64_t* inpb = (uint64_t*)p; p += 4*PW1*8;
  uint64_t* hs0b = (uint64_t*)p; p += 4*PW1*8;
  uint64_t* zs0b = (uint64_t*)p; p += 4*PW1*8;
  uint64_t* hs1b = (uint64_t*)p; p += 4*PW8*8;
  uint64_t* zs1b = (uint64_t*)p; p += 4*PW2*8;
  int*   eidx = (int*)p;   p += (size_t)NE*4;
  int*   csrc = (int*)p;   p += (size_t)NE*4;
  float* cw   = (float*)p; p += (size_t)NE*4;
  int*   cnt  = (int*)p;   p += (size_t)(NN+2)*4;
  int*   rp   = (int*)p;   p += (size_t)(NN+2)*4;
  int*   cur  = (int*)p;   p += (size_t)(NN+2)*4;

  // host-side key chain: key=(0,42); kt=fold_in(key,t); k1,k2=split(kt)
  K8 K1, K2;
  for (int t=0;t<4;t++){
    uint32_t kt0,kt1;
    tf2x32(0u, 42u, 0u, (uint32_t)t, kt0, kt1);
#if JAX_PARTITIONABLE
    tf2x32(kt0, kt1, 0u, 0u, K1.a[t], K1.b[t]);
    tf2x32(kt0, kt1, 0u, 1u, K2.a[t], K2.b[t]);
#else
    uint32_t A0,B0,A1,B1;
    tf2x32(kt0, kt1, 0u, 2u, A0, B0);
    tf2x32(kt0, kt1, 1u, 3u, A1, B1);
    K1.a[t]=A0; K1.b[t]=A1; K2.a[t]=B0; K2.b[t]=B1;
#endif
  }

  // CSR build (deterministic via per-row sort by edge id)
  hipMemsetAsync(cnt, 0, (size_t)NN*4, stream);
  k_hist   <<<(NE+255)/256, 256, 0, stream>>>(edst, cnt);
  k_scan   <<<1, 1024, 0, stream>>>(cnt, rp, cur);
  k_scatter<<<(NE+255)/256, 256, 0, stream>>>(edst, cur, eidx);
  k_sortrow<<<(NN+255)/256, 256, 0, stream>>>(rp, eidx, esrc, ew, csrc, cw);

  // stage-major pipeline, all T=4 per kernel, LIF state in registers (fp32)
  k_pois_x<<<TOT/256, 256, 0, stream>>>(x, inpb, K1);
  k_h0    <<<NN, 256, 0, stream>>>(rp, csrc, cw, inpb, hs0b, K2);
  k_z0    <<<NN/4, 256, 0, stream>>>(hs0b, W1, zs0b);
  k_h1    <<<NN, 512, 0, stream>>>(rp, csrc, cw, zs0b, hs0b, hs1b);
  k_z1    <<<NN/4, 128, 0, stream>>>(hs1b, W2, zs1b);
  k_dec_y <<<NL, 128, 0, stream>>>(ns, nt, zs1b, Wd, bd, wrec, out);
}

// Round 4
// 4977.347 us; speedup vs baseline: 1.4387x; 1.4387x over previous
//
#include <hip/hip_runtime.h>
#include <stdint.h>
#include <math.h>

// Problem constants
#define NN    50000       // N_NODES
#define NE    400000      // N_EDGES
#define NL    50000       // N_LINKS
#define TOT   12800000    // NN*256
#define PW1   200000ull   // words per 256-bit plane  (NN*4)
#define PW8   400000ull   // words per 512-bit plane  (NN*8)
#define PW2   100000ull   // words per 128-bit plane  (NN*2)

#define JAX_PARTITIONABLE 1

struct K8 { uint32_t a[4]; uint32_t b[4]; };

// ---------------- Threefry-2x32 (20 rounds) ----------------
__host__ __device__ inline uint32_t rotl32(uint32_t x, int r){ return (x<<r)|(x>>(32-r)); }

__host__ __device__ inline void tf2x32(uint32_t k0, uint32_t k1, uint32_t x0, uint32_t x1,
                                       uint32_t &o0, uint32_t &o1) {
  uint32_t k2 = k0 ^ k1 ^ 0x1BD11BDAu;
  x0 += k0; x1 += k1;
#define TFR(r) { x0 += x1; x1 = rotl32(x1,(r)); x1 ^= x0; }
  TFR(13) TFR(15) TFR(26) TFR(6)
  x0 += k1; x1 += k2 + 1u;
  TFR(17) TFR(29) TFR(16) TFR(24)
  x0 += k2; x1 += k0 + 2u;
  TFR(13) TFR(15) TFR(26) TFR(6)
  x0 += k0; x1 += k1 + 3u;
  TFR(17) TFR(29) TFR(16) TFR(24)
  x0 += k1; x1 += k2 + 4u;
  TFR(13) TFR(15) TFR(26) TFR(6)
  x0 += k2; x1 += k0 + 5u;
#undef TFR
  o0 = x0; o1 = x1;
}

__device__ inline float u01(uint32_t b){
  return __uint_as_float((b>>9) | 0x3f800000u) - 1.0f;   // [1,2) - 1, exact
}

__device__ inline uint32_t jax_bits32(uint32_t ka, uint32_t kb, uint32_t i, uint32_t total){
#if JAX_PARTITIONABLE
  uint32_t o0,o1; tf2x32(ka,kb, 0u, i, o0,o1); return o0^o1;
#else
  uint32_t h = total>>1; uint32_t o0,o1;
  if (i < h){ tf2x32(ka,kb, i, i+h, o0,o1); return o0; }
  else      { tf2x32(ka,kb, i-h, i, o0,o1); return o1; }
#endif
}

__device__ inline double shflxor_d(double x, int m){
  union { double d; int i[2]; } u; u.d = x;
  u.i[0] = __shfl_xor(u.i[0], m, 64);
  u.i[1] = __shfl_xor(u.i[1], m, 64);
  return u.d;
}

// exact fp32 LIF step: v = fl(fl(v*0.5)+a); d = fl(v-0.2); s=(d>=0); v = s?d:v
__device__ inline bool lif32(float &v, float a){
  v = __fadd_rn(__fmul_rn(v, 0.5f), a);
  float d = __fsub_rn(v, 0.2f);
  bool s = (d >= 0.0f);
  v = s ? d : v;
  return s;
}

// ---------------- CSR build (by dst), deterministic edge order ----------------
__global__ __launch_bounds__(256) void k_hist(const int* __restrict__ dst, int* __restrict__ cnt){
  int e = blockIdx.x*256 + threadIdx.x;
  if (e < NE) atomicAdd(&cnt[dst[e]], 1);
}

__global__ __launch_bounds__(1024) void k_scan(const int* __restrict__ cnt,
    int* __restrict__ rp, int* __restrict__ cur){
  __shared__ int buf[1024];
  __shared__ int carry;
  int tid = threadIdx.x;
  if (tid==0) carry = 0;
  __syncthreads();
  for (int base=0; base<NN; base+=1024){
    int v = (base+tid < NN) ? cnt[base+tid] : 0;
    buf[tid] = v; __syncthreads();
    for (int off=1; off<1024; off<<=1){
      int t = (tid>=off) ? buf[tid-off] : 0;
      __syncthreads();
      buf[tid] += t;
      __syncthreads();
    }
    int excl = buf[tid] - v + carry;
    if (base+tid < NN){ rp[base+tid] = excl; cur[base+tid] = excl; }
    __syncthreads();
    if (tid==0) carry += buf[1023];
    __syncthreads();
  }
  if (tid==0) rp[NN] = NE;
}

__global__ __launch_bounds__(256) void k_scatter(const int* __restrict__ dst,
    int* __restrict__ cur, int* __restrict__ eidx){
  int e = blockIdx.x*256 + threadIdx.x;
  if (e < NE){ int p = atomicAdd(&cur[dst[e]], 1); eidx[p] = e; }
}

__global__ __launch_bounds__(256) void k_sortrow(const int* __restrict__ rp,
    int* __restrict__ eidx, const int* __restrict__ esrc, const float* __restrict__ ew,
    int* __restrict__ csrc, float* __restrict__ cw){
  int n = blockIdx.x*256 + threadIdx.x;
  if (n >= NN) return;
  int lo = rp[n], hi = rp[n+1];
  for (int a=lo+1; a<hi; a++){
    int k = eidx[a]; int b = a-1;
    while (b>=lo && eidx[b]>k){ eidx[b+1]=eidx[b]; b--; }
    eidx[b+1] = k;
  }
  for (int p=lo; p<hi; p++){ int e = eidx[p]; csrc[p] = esrc[e]; cw[p] = ew[e]; }
}

// ---------------- Stage A: inp(t) = poisson(x, k1[t]) ----------------
__global__ __launch_bounds__(256) void k_pois_x(const float* __restrict__ x,
    uint64_t* __restrict__ bits, K8 K){
  uint32_t i = blockIdx.x*256u + threadIdx.x;
  float xv = x[i];
  #pragma unroll
  for (int t=0;t<4;t++){
    bool b = (u01(jax_bits32(K.a[t],K.b[t], i, TOT)) <= xv);
    uint64_t w = __ballot(b);
    if ((threadIdx.x & 63u)==0u) bits[(size_t)t*PW1 + (i>>6)] = w;
  }
}

// ---------------- Stage B: h0(t) fp32 gather (edge order) + poisson(h0,k2) ----------------
__global__ __launch_bounds__(256) void k_h0(const int* __restrict__ rp,
    const int* __restrict__ csrc, const float* __restrict__ cw,
    const uint64_t* __restrict__ inb, uint64_t* __restrict__ outb, K8 K){
  int n = blockIdx.x, f = threadIdx.x;
  int wi = f>>6, sh = f&63;
  int lo = rp[n], hi = rp[n+1];
  float a0=0.f,a1=0.f,a2=0.f,a3=0.f;
  for (int p=lo;p<hi;p++){
    int s = csrc[p]; float w = cw[p];
    const uint64_t* bp = inb + (size_t)s*4 + wi;
    a0 = __fadd_rn(a0, ((bp[0*PW1]>>sh)&1ull) ? w : 0.0f);
    a1 = __fadd_rn(a1, ((bp[1*PW1]>>sh)&1ull) ? w : 0.0f);
    a2 = __fadd_rn(a2, ((bp[2*PW1]>>sh)&1ull) ? w : 0.0f);
    a3 = __fadd_rn(a3, ((bp[3*PW1]>>sh)&1ull) ? w : 0.0f);
  }
  float acc[4] = {a0,a1,a2,a3};
  uint32_t i = (uint32_t)n*256u + (uint32_t)f;
  #pragma unroll
  for (int t=0;t<4;t++){
    bool b = (u01(jax_bits32(K.a[t],K.b[t], i, TOT)) <= acc[t]);
    uint64_t w = __ballot(b);
    if (sh==0) outb[(size_t)t*PW1 + (size_t)n*4 + wi] = w;
  }
}

// ---------------- Stage C: z0 = LIF_t(hs0 @ W1)  (K=256, M=256) ----------------
// Chunked register-preload: loads never sit in the add-dependency chain.
// Sum order per (t,i): ascending k, skipping zeros via +0.0f select (exact identity).
__global__ __launch_bounds__(256) void k_z0(const uint64_t* __restrict__ inb,
    const float* __restrict__ W, uint64_t* __restrict__ outb){
  int j = threadIdx.x;
  int n0 = blockIdx.x*4;
  float acc[4][4];                                // [t][i]
  #pragma unroll
  for (int t=0;t<4;t++)
    #pragma unroll
    for (int i=0;i<4;i++) acc[t][i] = 0.0f;

  for (int kw=0;kw<4;kw++){
    uint64_t w[4][4];
    #pragma unroll
    for (int t=0;t<4;t++)
      #pragma unroll
      for (int i=0;i<4;i++)
        w[t][i] = inb[(size_t)t*PW1 + (size_t)(n0+i)*4 + kw];
    const float* Wp = W + (size_t)(kw*64)*256 + j;
    for (int c=0;c<4;c++){
      float wr[16];
      #pragma unroll
      for (int q=0;q<16;q++) wr[q] = Wp[(size_t)(c*16+q)*256];
      #pragma unroll
      for (int q=0;q<16;q++){
        int kk = c*16+q;
        #pragma unroll
        for (int t=0;t<4;t++)
          #pragma unroll
          for (int i=0;i<4;i++)
            acc[t][i] = __fadd_rn(acc[t][i], ((w[t][i]>>kk)&1ull) ? wr[q] : 0.0f);
      }
    }
  }

  float v[4] = {0.f,0.f,0.f,0.f};
  for (int t=0;t<4;t++){
    #pragma unroll
    for (int i=0;i<4;i++){
      bool s = lif32(v[i], acc[t][i]);
      uint64_t bw = __ballot(s);
      if ((j&63)==0) outb[(size_t)t*PW1 + (size_t)(n0+i)*4 + (j>>6)] = bw;
    }
  }
}

// ---------------- Stage D: h1(t) fp32 gather over concat(zs0,hs0), LIF -> hs1 ----------------
__global__ __launch_bounds__(512) void k_h1(const int* __restrict__ rp,
    const int* __restrict__ csrc, const float* __restrict__ cw,
    const uint64_t* __restrict__ zs0b, const uint64_t* __restrict__ hs0b,
    uint64_t* __restrict__ hs1b){
  int n = blockIdx.x, f = threadIdx.x;           // f in [0,512)
  int wi = f>>6, sh = f&63;
  const uint64_t* plane = (wi<4) ? zs0b : hs0b;
  int wo = (wi<4) ? wi : wi-4;
  int lo = rp[n], hi = rp[n+1];
  float a[4] = {0.f,0.f,0.f,0.f};
  for (int p=lo;p<hi;p++){
    int s = csrc[p]; float w = cw[p];
    const uint64_t* bp = plane + (size_t)s*4 + wo;
    #pragma unroll
    for (int t=0;t<4;t++)
      a[t] = __fadd_rn(a[t], ((bp[(size_t)t*PW1]>>sh)&1ull) ? w : 0.0f);
  }
  float v = 0.0f;
  #pragma unroll
  for (int t=0;t<4;t++){
    bool s = lif32(v, a[t]);
    uint64_t bw = __ballot(s);
    if (sh==0) hs1b[(size_t)t*PW8 + (size_t)n*8 + wi] = bw;
  }
}

// ---------------- Stage E: z1 = LIF_t(hs1 @ W2)  (K=512, M=128) ----------------
__global__ __launch_bounds__(128) void k_z1(const uint64_t* __restrict__ inb,
    const float* __restrict__ W, uint64_t* __restrict__ outb){
  int j = threadIdx.x;
  int n0 = blockIdx.x*4;
  float acc[4][4];
  #pragma unroll
  for (int t=0;t<4;t++)
    #pragma unroll
    for (int i=0;i<4;i++) acc[t][i] = 0.0f;

  for (int kw=0;kw<8;kw++){
    uint64_t w[4][4];
    #pragma unroll
    for (int t=0;t<4;t++)
      #pragma unroll
      for (int i=0;i<4;i++)
        w[t][i] = inb[(size_t)t*PW8 + (size_t)(n0+i)*8 + kw];
    const float* Wp = W + (size_t)(kw*64)*128 + j;
    for (int c=0;c<4;c++){
      float wr[16];
      #pragma unroll
      for (int q=0;q<16;q++) wr[q] = Wp[(size_t)(c*16+q)*128];
      #pragma unroll
      for (int q=0;q<16;q++){
        int kk = c*16+q;
        #pragma unroll
        for (int t=0;t<4;t++)
          #pragma unroll
          for (int i=0;i<4;i++)
            acc[t][i] = __fadd_rn(acc[t][i], ((w[t][i]>>kk)&1ull) ? wr[q] : 0.0f);
      }
    }
  }

  float v[4] = {0.f,0.f,0.f,0.f};
  for (int t=0;t<4;t++){
    #pragma unroll
    for (int i=0;i<4;i++){
      bool s = lif32(v[i], acc[t][i]);
      uint64_t bw = __ballot(s);
      if ((j&63)==0) outb[(size_t)t*PW2 + (size_t)(n0+i)*2 + (j>>6)] = bw;
    }
  }
}

// ---------------- Stage F: decoder + y + sigmoid ----------------
// block = 128 threads: wave0 = row i (ns), wave1 = row i+L (nt)
__global__ __launch_bounds__(128) void k_dec_y(const int* __restrict__ ns,
    const int* __restrict__ nt, const uint64_t* __restrict__ zs1b,
    const float* __restrict__ Wd, const float* __restrict__ bd,
    const float* __restrict__ wrec, float* __restrict__ out){
  int i = blockIdx.x;
  int tid = threadIdx.x;
  int half = tid>>6, j = tid&63;
  int node = half ? nt[i] : ns[i];
  float bdj = bd[j];
  double wrecj = (double)wrec[j];
  __shared__ uint64_t sw[2];
  float v = 0.0f;
  double ysum = 0.0;
  for (int t=0;t<4;t++){
    uint64_t w0 = zs1b[(size_t)t*PW2 + (size_t)node*2 + 0];
    uint64_t w1 = zs1b[(size_t)t*PW2 + (size_t)node*2 + 1];
    float acc = 0.0f;                          // k-sum first, bias after
    for (int c=0;c<4;c++){
      float wr[16];
      #pragma unroll
      for (int q=0;q<16;q++) wr[q] = Wd[(size_t)(c*16+q)*64 + j];
      #pragma unroll
      for (int q=0;q<16;q++)
        acc = __fadd_rn(acc, ((w0>>(c*16+q))&1ull) ? wr[q] : 0.0f);
    }
    for (int c=0;c<4;c++){
      float wr[16];
      #pragma unroll
      for (int q=0;q<16;q++) wr[q] = Wd[(size_t)(64+c*16+q)*64 + j];
      #pragma unroll
      for (int q=0;q<16;q++)
        acc = __fadd_rn(acc, ((w1>>(c*16+q))&1ull) ? wr[q] : 0.0f);
    }
    acc = __fadd_rn(acc, bdj);
    bool s = lif32(v, acc);
    uint64_t bw = __ballot(s);
    if (j==0) sw[half] = bw;
    __syncthreads();
    uint64_t m = sw[0] & sw[1];
    __syncthreads();
    double term = ((m>>j)&1ull) ? wrecj : 0.0;
    #pragma unroll
    for (int off=1; off<64; off<<=1) term += shflxor_d(term, off);
    ysum += term;
  }
  if (tid==0) out[i] = (float)(1.0/(1.0 + exp(-0.25*ysum)));
}

// ---------------- Launcher ----------------
extern "C" void kernel_launch(void* const* d_in, const int* in_sizes, int n_in,
                              void* d_out, int out_size, void* d_ws, size_t ws_size,
                              hipStream_t stream) {
  const float* x    = (const float*)d_in[0];
  const float* W1   = (const float*)d_in[1];
  const float* W2   = (const float*)d_in[2];
  const float* Wd   = (const float*)d_in[3];
  const float* bd   = (const float*)d_in[4];
  const float* wrec = (const float*)d_in[5];
  const float* ew   = (const float*)d_in[6];
  const int* esrc   = (const int*)d_in[7];
  const int* edst   = (const int*)d_in[8];
  const int* ns     = (const int*)d_in[9];
  const int* nt     = (const int*)d_in[10];
  float* out = (float*)d_out;
  (void)in_sizes; (void)n_in; (void)out_size; (void)ws_size;

  // workspace layout (~41 MB)
  char* p = (char*)d_ws;
  uint64_t* inpb = (uint64_t*)p; p += 4*PW1*8;
  uint64_t* hs0b = (uint64_t*)p; p += 4*PW1*8;
  uint64_t* zs0b = (uint64_t*)p; p += 4*PW1*8;
  uint64_t* hs1b = (uint64_t*)p; p += 4*PW8*8;
  uint64_t* zs1b = (uint64_t*)p; p += 4*PW2*8;
  int*   eidx = (int*)p;   p += (size_t)NE*4;
  int*   csrc = (int*)p;   p += (size_t)NE*4;
  float* cw   = (float*)p; p += (size_t)NE*4;
  int*   cnt  = (int*)p;   p += (size_t)(NN+2)*4;
  int*   rp   = (int*)p;   p += (size_t)(NN+2)*4;
  int*   cur  = (int*)p;   p += (size_t)(NN+2)*4;

  // host-side key chain: key=(0,42); kt=fold_in(key,t); k1,k2=split(kt)
  K8 K1, K2;
  for (int t=0;t<4;t++){
    uint32_t kt0,kt1;
    tf2x32(0u, 42u, 0u, (uint32_t)t, kt0, kt1);
#if JAX_PARTITIONABLE
    tf2x32(kt0, kt1, 0u, 0u, K1.a[t], K1.b[t]);
    tf2x32(kt0, kt1, 0u, 1u, K2.a[t], K2.b[t]);
#else
    uint32_t A0,B0,A1,B1;
    tf2x32(kt0, kt1, 0u, 2u, A0, B0);
    tf2x32(kt0, kt1, 1u, 3u, A1, B1);
    K1.a[t]=A0; K1.b[t]=A1; K2.a[t]=B0; K2.b[t]=B1;
#endif
  }

  // CSR build (deterministic via per-row sort by edge id)
  hipMemsetAsync(cnt, 0, (size_t)NN*4, stream);
  k_hist   <<<(NE+255)/256, 256, 0, stream>>>(edst, cnt);
  k_scan   <<<1, 1024, 0, stream>>>(cnt, rp, cur);
  k_scatter<<<(NE+255)/256, 256, 0, stream>>>(edst, cur, eidx);
  k_sortrow<<<(NN+255)/256, 256, 0, stream>>>(rp, eidx, esrc, ew, csrc, cw);

  // stage-major pipeline, all T=4 per kernel, LIF state in registers (fp32)
  k_pois_x<<<TOT/256, 256, 0, stream>>>(x, inpb, K1);
  k_h0    <<<NN, 256, 0, stream>>>(rp, csrc, cw, inpb, hs0b, K2);
  k_z0    <<<NN/4, 256, 0, stream>>>(hs0b, W1, zs0b);
  k_h1    <<<NN, 512, 0, stream>>>(rp, csrc, cw, zs0b, hs0b, hs1b);
  k_z1    <<<NN/4, 128, 0, stream>>>(hs1b, W2, zs1b);
  k_dec_y <<<NL, 128, 0, stream>>>(ns, nt, zs1b, Wd, bd, wrec, out);
}

// Round 5
// 3300.282 us; speedup vs baseline: 2.1698x; 1.5082x over previous
//
#include <hip/hip_runtime.h>
#include <stdint.h>
#include <math.h>

// Problem constants
#define NN    50000       // N_NODES
#define NE    400000      // N_EDGES
#define NL    50000       // N_LINKS
#define TOT   12800000    // NN*256

#define JAX_PARTITIONABLE 1

struct K8 { uint32_t a[4]; uint32_t b[4]; };

// ---------------- Threefry-2x32 (20 rounds) ----------------
__host__ __device__ inline uint32_t rotl32(uint32_t x, int r){ return (x<<r)|(x>>(32-r)); }

__host__ __device__ inline void tf2x32(uint32_t k0, uint32_t k1, uint32_t x0, uint32_t x1,
                                       uint32_t &o0, uint32_t &o1) {
  uint32_t k2 = k0 ^ k1 ^ 0x1BD11BDAu;
  x0 += k0; x1 += k1;
#define TFR(r) { x0 += x1; x1 = rotl32(x1,(r)); x1 ^= x0; }
  TFR(13) TFR(15) TFR(26) TFR(6)
  x0 += k1; x1 += k2 + 1u;
  TFR(17) TFR(29) TFR(16) TFR(24)
  x0 += k2; x1 += k0 + 2u;
  TFR(13) TFR(15) TFR(26) TFR(6)
  x0 += k0; x1 += k1 + 3u;
  TFR(17) TFR(29) TFR(16) TFR(24)
  x0 += k1; x1 += k2 + 4u;
  TFR(13) TFR(15) TFR(26) TFR(6)
  x0 += k2; x1 += k0 + 5u;
#undef TFR
  o0 = x0; o1 = x1;
}

__device__ inline float u01(uint32_t b){
  return __uint_as_float((b>>9) | 0x3f800000u) - 1.0f;   // [1,2) - 1, exact
}

__device__ inline uint32_t jax_bits32(uint32_t ka, uint32_t kb, uint32_t i, uint32_t total){
#if JAX_PARTITIONABLE
  uint32_t o0,o1; tf2x32(ka,kb, 0u, i, o0,o1); return o0^o1;
#else
  uint32_t h = total>>1; uint32_t o0,o1;
  if (i < h){ tf2x32(ka,kb, i, i+h, o0,o1); return o0; }
  else      { tf2x32(ka,kb, i-h, i, o0,o1); return o1; }
#endif
}

__device__ inline double shflxor_d(double x, int m){
  union { double d; int i[2]; } u; u.d = x;
  u.i[0] = __shfl_xor(u.i[0], m, 64);
  u.i[1] = __shfl_xor(u.i[1], m, 64);
  return u.d;
}

// exact fp32 LIF step: v = fl(fl(v*0.5)+a); d = fl(v-0.2); s=(d>=0); v = s?d:v
__device__ inline bool lif32(float &v, float a){
  v = __fadd_rn(__fmul_rn(v, 0.5f), a);
  float d = __fsub_rn(v, 0.2f);
  bool s = (d >= 0.0f);
  v = s ? d : v;
  return s;
}

// force a value to live in a VGPR (defeats scalar-ization of uniform values)
#define FORCE_V(x) asm volatile("" : "+v"(x))

// ---------------- CSR build (by dst), deterministic edge order ----------------
__global__ __launch_bounds__(256) void k_hist(const int* __restrict__ dst, int* __restrict__ cnt){
  int e = blockIdx.x*256 + threadIdx.x;
  if (e < NE) atomicAdd(&cnt[dst[e]], 1);
}

__global__ __launch_bounds__(1024) void k_scan(const int* __restrict__ cnt,
    int* __restrict__ rp, int* __restrict__ cur){
  __shared__ int buf[1024];
  __shared__ int carry;
  int tid = threadIdx.x;
  if (tid==0) carry = 0;
  __syncthreads();
  for (int base=0; base<NN; base+=1024){
    int v = (base+tid < NN) ? cnt[base+tid] : 0;
    buf[tid] = v; __syncthreads();
    for (int off=1; off<1024; off<<=1){
      int t = (tid>=off) ? buf[tid-off] : 0;
      __syncthreads();
      buf[tid] += t;
      __syncthreads();
    }
    int excl = buf[tid] - v + carry;
    if (base+tid < NN){ rp[base+tid] = excl; cur[base+tid] = excl; }
    __syncthreads();
    if (tid==0) carry += buf[1023];
    __syncthreads();
  }
  if (tid==0) rp[NN] = NE;
}

__global__ __launch_bounds__(256) void k_scatter(const int* __restrict__ dst,
    int* __restrict__ cur, int* __restrict__ eidx){
  int e = blockIdx.x*256 + threadIdx.x;
  if (e < NE){ int p = atomicAdd(&cur[dst[e]], 1); eidx[p] = e; }
}

__global__ __launch_bounds__(256) void k_sortrow(const int* __restrict__ rp,
    int* __restrict__ eidx, const int* __restrict__ esrc, const float* __restrict__ ew,
    int* __restrict__ csrc, float* __restrict__ cw){
  int n = blockIdx.x*256 + threadIdx.x;
  if (n >= NN) return;
  int lo = rp[n], hi = rp[n+1];
  for (int a=lo+1; a<hi; a++){
    int k = eidx[a]; int b = a-1;
    while (b>=lo && eidx[b]>k){ eidx[b+1]=eidx[b]; b--; }
    eidx[b+1] = k;
  }
  for (int p=lo; p<hi; p++){ int e = eidx[p]; csrc[p] = esrc[e]; cw[p] = ew[e]; }
}

// Plane layouts (t innermost, 32B per (node,word)):
//   inpb/hs0b/zs0b : [node][w(4)][t(4)]   (NN*16 words)
//   hs1b           : [node][w(8)][t(4)]   (NN*32 words)
//   zs1b           : [node][w(2)][t(4)]   (NN*8  words)

// ---------------- Stage A: inp(t) = poisson(x, k1[t]) ----------------
__global__ __launch_bounds__(256) void k_pois_x(const float* __restrict__ x,
    uint64_t* __restrict__ bits, K8 K){
  int n = blockIdx.x, f = threadIdx.x;
  uint32_t i = (uint32_t)n*256u + (uint32_t)f;
  float xv = x[i];
  uint64_t pack[4];
  #pragma unroll
  for (int t=0;t<4;t++){
    bool b = (u01(jax_bits32(K.a[t],K.b[t], i, TOT)) <= xv);
    pack[t] = __ballot(b);
  }
  if ((f & 63)==0){
    uint64_t* dst = bits + ((size_t)n*4 + (f>>6))*4;
    #pragma unroll
    for (int t=0;t<4;t++) dst[t] = pack[t];
  }
}

// ---------------- Stage B: h0(t) fp32 gather (edge order) + poisson(h0,k2) ----------------
__global__ __launch_bounds__(256) void k_h0(const int* __restrict__ rp,
    const int* __restrict__ csrc, const float* __restrict__ cw,
    const uint64_t* __restrict__ inb, uint64_t* __restrict__ outb, K8 K){
  int n = blockIdx.x, f = threadIdx.x;
  int wi = f>>6, sh = f&63;
  int lo = rp[n], hi = rp[n+1];
  float a[4] = {0.f,0.f,0.f,0.f};
  for (int p=lo;p<hi;p++){
    int s = csrc[p]; float w = cw[p];
    const uint64_t* bp = inb + ((size_t)s*4 + wi)*4;   // 4 t-words, 32B contiguous
    uint64_t w0=bp[0], w1=bp[1], w2=bp[2], w3=bp[3];
    a[0] = __fadd_rn(a[0], ((w0>>sh)&1ull) ? w : 0.0f);
    a[1] = __fadd_rn(a[1], ((w1>>sh)&1ull) ? w : 0.0f);
    a[2] = __fadd_rn(a[2], ((w2>>sh)&1ull) ? w : 0.0f);
    a[3] = __fadd_rn(a[3], ((w3>>sh)&1ull) ? w : 0.0f);
  }
  uint32_t i = (uint32_t)n*256u + (uint32_t)f;
  uint64_t pack[4];
  #pragma unroll
  for (int t=0;t<4;t++){
    bool b = (u01(jax_bits32(K.a[t],K.b[t], i, TOT)) <= a[t]);
    pack[t] = __ballot(b);
  }
  if (sh==0){
    uint64_t* dst = outb + ((size_t)n*4 + wi)*4;
    #pragma unroll
    for (int t=0;t<4;t++) dst[t] = pack[t];
  }
}

// ---------------- Stage C: z0 = LIF_t(hs0 @ W1)  (K=256, M=256) ----------------
// Pure-VALU masked sum: bfe -> cvt -> fmac(bitf, wr, acc). Exact identity with
// the fadd(bit?wr:0) sequence. Words forced into VGPRs to avoid SALU path.
__global__ __launch_bounds__(256) void k_z0(const uint64_t* __restrict__ inb,
    const float* __restrict__ W, uint64_t* __restrict__ outb){
  int j = threadIdx.x;
  int n0 = blockIdx.x*4;
  float acc[4][4];                                // [t][i]
  #pragma unroll
  for (int t=0;t<4;t++)
    #pragma unroll
    for (int i=0;i<4;i++) acc[t][i] = 0.0f;

  for (int kw=0;kw<4;kw++){
    uint32_t wlo[4][4], whi[4][4];                // [i][t]
    #pragma unroll
    for (int i=0;i<4;i++){
      const uint64_t* bp = inb + (((size_t)(n0+i))*4 + kw)*4;
      #pragma unroll
      for (int t=0;t<4;t++){
        uint64_t w8 = bp[t];
        wlo[i][t] = (uint32_t)w8;
        whi[i][t] = (uint32_t)(w8>>32);
        FORCE_V(wlo[i][t]); FORCE_V(whi[i][t]);
      }
    }
    const float* Wp = W + (size_t)(kw*64)*256 + j;
    #pragma unroll
    for (int h=0;h<2;h++){
      #pragma unroll
      for (int c=0;c<2;c++){
        float wr[16];
        #pragma unroll
        for (int q=0;q<16;q++) wr[q] = Wp[(size_t)(h*32+c*16+q)*256];
        #pragma unroll
        for (int q=0;q<16;q++){
          int b = c*16+q;
          #pragma unroll
          for (int i=0;i<4;i++){
            #pragma unroll
            for (int t=0;t<4;t++){
              float bitf = (float)((( (h? whi[i][t] : wlo[i][t]) >> b) & 1u));
              acc[t][i] = __fmaf_rn(bitf, wr[q], acc[t][i]);
            }
          }
        }
      }
    }
  }

  int wi = j>>6;
  #pragma unroll
  for (int i=0;i<4;i++){
    float v = 0.0f;
    uint64_t pack[4];
    #pragma unroll
    for (int t=0;t<4;t++){
      bool s = lif32(v, acc[t][i]);
      pack[t] = __ballot(s);
    }
    if ((j&63)==0){
      uint64_t* dst = outb + (((size_t)(n0+i))*4 + wi)*4;
      #pragma unroll
      for (int t=0;t<4;t++) dst[t] = pack[t];
    }
  }
}

// ---------------- Stage D: h1(t) gather over concat(zs0,hs0), LIF -> hs1 ----------------
__global__ __launch_bounds__(512) void k_h1(const int* __restrict__ rp,
    const int* __restrict__ csrc, const float* __restrict__ cw,
    const uint64_t* __restrict__ zs0b, const uint64_t* __restrict__ hs0b,
    uint64_t* __restrict__ hs1b){
  int n = blockIdx.x, f = threadIdx.x;           // f in [0,512)
  int wi = f>>6, sh = f&63;
  const uint64_t* plane = (wi<4) ? zs0b : hs0b;
  int wo = wi & 3;
  int lo = rp[n], hi = rp[n+1];
  float a[4] = {0.f,0.f,0.f,0.f};
  for (int p=lo;p<hi;p++){
    int s = csrc[p]; float w = cw[p];
    const uint64_t* bp = plane + ((size_t)s*4 + wo)*4;  // 32B contiguous
    uint64_t w0=bp[0], w1=bp[1], w2=bp[2], w3=bp[3];
    a[0] = __fadd_rn(a[0], ((w0>>sh)&1ull) ? w : 0.0f);
    a[1] = __fadd_rn(a[1], ((w1>>sh)&1ull) ? w : 0.0f);
    a[2] = __fadd_rn(a[2], ((w2>>sh)&1ull) ? w : 0.0f);
    a[3] = __fadd_rn(a[3], ((w3>>sh)&1ull) ? w : 0.0f);
  }
  float v = 0.0f;
  uint64_t pack[4];
  #pragma unroll
  for (int t=0;t<4;t++){
    bool s = lif32(v, a[t]);
    pack[t] = __ballot(s);
  }
  if (sh==0){
    uint64_t* dst = hs1b + ((size_t)n*8 + wi)*4;
    #pragma unroll
    for (int t=0;t<4;t++) dst[t] = pack[t];
  }
}

// ---------------- Stage E: z1 = LIF_t(hs1 @ W2)  (K=512, M=128) ----------------
__global__ __launch_bounds__(128) void k_z1(const uint64_t* __restrict__ inb,
    const float* __restrict__ W, uint64_t* __restrict__ outb){
  int j = threadIdx.x;
  int n0 = blockIdx.x*4;
  float acc[4][4];
  #pragma unroll
  for (int t=0;t<4;t++)
    #pragma unroll
    for (int i=0;i<4;i++) acc[t][i] = 0.0f;

  for (int kw=0;kw<8;kw++){
    uint32_t wlo[4][4], whi[4][4];
    #pragma unroll
    for (int i=0;i<4;i++){
      const uint64_t* bp = inb + (((size_t)(n0+i))*8 + kw)*4;
      #pragma unroll
      for (int t=0;t<4;t++){
        uint64_t w8 = bp[t];
        wlo[i][t] = (uint32_t)w8;
        whi[i][t] = (uint32_t)(w8>>32);
        FORCE_V(wlo[i][t]); FORCE_V(whi[i][t]);
      }
    }
    const float* Wp = W + (size_t)(kw*64)*128 + j;
    #pragma unroll
    for (int h=0;h<2;h++){
      #pragma unroll
      for (int c=0;c<2;c++){
        float wr[16];
        #pragma unroll
        for (int q=0;q<16;q++) wr[q] = Wp[(size_t)(h*32+c*16+q)*128];
        #pragma unroll
        for (int q=0;q<16;q++){
          int b = c*16+q;
          #pragma unroll
          for (int i=0;i<4;i++){
            #pragma unroll
            for (int t=0;t<4;t++){
              float bitf = (float)((( (h? whi[i][t] : wlo[i][t]) >> b) & 1u));
              acc[t][i] = __fmaf_rn(bitf, wr[q], acc[t][i]);
            }
          }
        }
      }
    }
  }

  int wi = j>>6;  // 0 or 1
  #pragma unroll
  for (int i=0;i<4;i++){
    float v = 0.0f;
    uint64_t pack[4];
    #pragma unroll
    for (int t=0;t<4;t++){
      bool s = lif32(v, acc[t][i]);
      pack[t] = __ballot(s);
    }
    if ((j&63)==0){
      uint64_t* dst = outb + (((size_t)(n0+i))*2 + wi)*4;
      #pragma unroll
      for (int t=0;t<4;t++) dst[t] = pack[t];
    }
  }
}

// ---------------- Stage F: decoder + y + sigmoid ----------------
// block = 128 threads: wave0 = row i (ns), wave1 = row i+L (nt); j = DEC column
__global__ __launch_bounds__(128) void k_dec_y(const int* __restrict__ ns,
    const int* __restrict__ nt, const uint64_t* __restrict__ zs1b,
    const float* __restrict__ Wd, const float* __restrict__ bd,
    const float* __restrict__ wrec, float* __restrict__ out){
  int i = blockIdx.x;
  int tid = threadIdx.x;
  int row = tid>>6, j = tid&63;
  int node = row ? nt[i] : ns[i];
  float bdj = bd[j];
  double wrecj = (double)wrec[j];
  __shared__ uint64_t sw[2];

  // load this node's zs1 row: 2 k-groups x 4 t  (64B contiguous)
  uint32_t wlo[2][4], whi[2][4];
  const uint64_t* bp = zs1b + (size_t)node*8;
  #pragma unroll
  for (int g=0;g<2;g++)
    #pragma unroll
    for (int t=0;t<4;t++){
      uint64_t w8 = bp[g*4+t];
      wlo[g][t] = (uint32_t)w8;
      whi[g][t] = (uint32_t)(w8>>32);
      FORCE_V(wlo[g][t]); FORCE_V(whi[g][t]);
    }

  float acc[4] = {0.f,0.f,0.f,0.f};
  #pragma unroll
  for (int g=0;g<2;g++){
    #pragma unroll
    for (int h=0;h<2;h++){
      #pragma unroll
      for (int c=0;c<2;c++){
        float wr[16];
        #pragma unroll
        for (int q=0;q<16;q++) wr[q] = Wd[(size_t)(g*64+h*32+c*16+q)*64 + j];
        #pragma unroll
        for (int q=0;q<16;q++){
          int b = c*16+q;
          #pragma unroll
          for (int t=0;t<4;t++){
            float bitf = (float)(((h? whi[g][t] : wlo[g][t]) >> b) & 1u);
            acc[t] = __fmaf_rn(bitf, wr[q], acc[t]);
          }
        }
      }
    }
  }

  float v = 0.0f;
  double ysum = 0.0;
  #pragma unroll
  for (int t=0;t<4;t++){
    float a = __fadd_rn(acc[t], bdj);
    bool s = lif32(v, a);
    uint64_t bw = __ballot(s);
    if (j==0) sw[row] = bw;
    __syncthreads();
    uint64_t m = sw[0] & sw[1];
    __syncthreads();
    double term = ((m>>j)&1ull) ? wrecj : 0.0;
    #pragma unroll
    for (int off=1; off<64; off<<=1) term += shflxor_d(term, off);
    ysum += term;
  }
  if (tid==0) out[i] = (float)(1.0/(1.0 + exp(-0.25*ysum)));
}

// ---------------- Launcher ----------------
extern "C" void kernel_launch(void* const* d_in, const int* in_sizes, int n_in,
                              void* d_out, int out_size, void* d_ws, size_t ws_size,
                              hipStream_t stream) {
  const float* x    = (const float*)d_in[0];
  const float* W1   = (const float*)d_in[1];
  const float* W2   = (const float*)d_in[2];
  const float* Wd   = (const float*)d_in[3];
  const float* bd   = (const float*)d_in[4];
  const float* wrec = (const float*)d_in[5];
  const float* ew   = (const float*)d_in[6];
  const int* esrc   = (const int*)d_in[7];
  const int* edst   = (const int*)d_in[8];
  const int* ns     = (const int*)d_in[9];
  const int* nt     = (const int*)d_in[10];
  float* out = (float*)d_out;
  (void)in_sizes; (void)n_in; (void)out_size; (void)ws_size;

  // workspace layout (~41 MB)
  char* p = (char*)d_ws;
  uint64_t* inpb = (uint64_t*)p; p += (size_t)NN*16*8;
  uint64_t* hs0b = (uint64_t*)p; p += (size_t)NN*16*8;
  uint64_t* zs0b = (uint64_t*)p; p += (size_t)NN*16*8;
  uint64_t* hs1b = (uint64_t*)p; p += (size_t)NN*32*8;
  uint64_t* zs1b = (uint64_t*)p; p += (size_t)NN*8*8;
  int*   eidx = (int*)p;   p += (size_t)NE*4;
  int*   csrc = (int*)p;   p += (size_t)NE*4;
  float* cw   = (float*)p; p += (size_t)NE*4;
  int*   cnt  = (int*)p;   p += (size_t)(NN+2)*4;
  int*   rp   = (int*)p;   p += (size_t)(NN+2)*4;
  int*   cur  = (int*)p;   p += (size_t)(NN+2)*4;

  // host-side key chain: key=(0,42); kt=fold_in(key,t); k1,k2=split(kt)
  K8 K1, K2;
  for (int t=0;t<4;t++){
    uint32_t kt0,kt1;
    tf2x32(0u, 42u, 0u, (uint32_t)t, kt0, kt1);
#if JAX_PARTITIONABLE
    tf2x32(kt0, kt1, 0u, 0u, K1.a[t], K1.b[t]);
    tf2x32(kt0, kt1, 0u, 1u, K2.a[t], K2.b[t]);
#else
    uint32_t A0,B0,A1,B1;
    tf2x32(kt0, kt1, 0u, 2u, A0, B0);
    tf2x32(kt0, kt1, 1u, 3u, A1, B1);
    K1.a[t]=A0; K1.b[t]=A1; K2.a[t]=B0; K2.b[t]=B1;
#endif
  }

  // CSR build (deterministic via per-row sort by edge id)
  hipMemsetAsync(cnt, 0, (size_t)NN*4, stream);
  k_hist   <<<(NE+255)/256, 256, 0, stream>>>(edst, cnt);
  k_scan   <<<1, 1024, 0, stream>>>(cnt, rp, cur);
  k_scatter<<<(NE+255)/256, 256, 0, stream>>>(edst, cur, eidx);
  k_sortrow<<<(NN+255)/256, 256, 0, stream>>>(rp, eidx, esrc, ew, csrc, cw);

  // stage-major pipeline, all T=4 per kernel, LIF state in registers (fp32)
  k_pois_x<<<NN, 256, 0, stream>>>(x, inpb, K1);
  k_h0    <<<NN, 256, 0, stream>>>(rp, csrc, cw, inpb, hs0b, K2);
  k_z0    <<<NN/4, 256, 0, stream>>>(hs0b, W1, zs0b);
  k_h1    <<<NN, 512, 0, stream>>>(rp, csrc, cw, zs0b, hs0b, hs1b);
  k_z1    <<<NN/4, 128, 0, stream>>>(hs1b, W2, zs1b);
  k_dec_y <<<NL, 128, 0, stream>>>(ns, nt, zs1b, Wd, bd, wrec, out);
}

// Round 6
// 3006.070 us; speedup vs baseline: 2.3822x; 1.0979x over previous
//
#include <hip/hip_runtime.h>
#include <stdint.h>
#include <math.h>

// Problem constants
#define NN    50000       // N_NODES
#define NE    400000      // N_EDGES
#define NL    50000       // N_LINKS
#define TOT   12800000    // NN*256

#define JAX_PARTITIONABLE 1

struct K8 { uint32_t a[4]; uint32_t b[4]; };

// ---------------- Threefry-2x32 (20 rounds) ----------------
__host__ __device__ inline uint32_t rotl32(uint32_t x, int r){ return (x<<r)|(x>>(32-r)); }

__host__ __device__ inline void tf2x32(uint32_t k0, uint32_t k1, uint32_t x0, uint32_t x1,
                                       uint32_t &o0, uint32_t &o1) {
  uint32_t k2 = k0 ^ k1 ^ 0x1BD11BDAu;
  x0 += k0; x1 += k1;
#define TFR(r) { x0 += x1; x1 = rotl32(x1,(r)); x1 ^= x0; }
  TFR(13) TFR(15) TFR(26) TFR(6)
  x0 += k1; x1 += k2 + 1u;
  TFR(17) TFR(29) TFR(16) TFR(24)
  x0 += k2; x1 += k0 + 2u;
  TFR(13) TFR(15) TFR(26) TFR(6)
  x0 += k0; x1 += k1 + 3u;
  TFR(17) TFR(29) TFR(16) TFR(24)
  x0 += k1; x1 += k2 + 4u;
  TFR(13) TFR(15) TFR(26) TFR(6)
  x0 += k2; x1 += k0 + 5u;
#undef TFR
  o0 = x0; o1 = x1;
}

__device__ inline float u01(uint32_t b){
  return __uint_as_float((b>>9) | 0x3f800000u) - 1.0f;   // [1,2) - 1, exact
}

__device__ inline uint32_t jax_bits32(uint32_t ka, uint32_t kb, uint32_t i, uint32_t total){
#if JAX_PARTITIONABLE
  uint32_t o0,o1; tf2x32(ka,kb, 0u, i, o0,o1); return o0^o1;
#else
  uint32_t h = total>>1; uint32_t o0,o1;
  if (i < h){ tf2x32(ka,kb, i, i+h, o0,o1); return o0; }
  else      { tf2x32(ka,kb, i-h, i, o0,o1); return o1; }
#endif
}

__device__ inline double shflxor_d(double x, int m){
  union { double d; int i[2]; } u; u.d = x;
  u.i[0] = __shfl_xor(u.i[0], m, 64);
  u.i[1] = __shfl_xor(u.i[1], m, 64);
  return u.d;
}

// exact fp32 LIF step: v = fl(fl(v*0.5)+a); d = fl(v-0.2); s=(d>=0); v = s?d:v
__device__ inline bool lif32(float &v, float a){
  v = __fadd_rn(__fmul_rn(v, 0.5f), a);
  float d = __fsub_rn(v, 0.2f);
  bool s = (d >= 0.0f);
  v = s ? d : v;
  return s;
}

// force a value to live in a VGPR (defeats scalar-ization of uniform values)
#define FORCE_V(x) asm volatile("" : "+v"(x))

// wr if bit b of w set, else +0.0f — v_bfe_i32 + v_and_b32 (2 full-rate VALU ops)
__device__ inline float bitmaskf(uint32_t w, int b, float wr){
#if __has_builtin(__builtin_amdgcn_sbfe)
  int m = __builtin_amdgcn_sbfe((int)w, b, 1);       // 0x00000000 or 0xFFFFFFFF
#else
  int m = ((int)(w << (31-b))) >> 31;
#endif
  return __int_as_float(__float_as_int(wr) & m);
}

// ---------------- CSR build (by dst), deterministic edge order ----------------
__global__ __launch_bounds__(256) void k_hist(const int* __restrict__ dst, int* __restrict__ cnt){
  int e = blockIdx.x*256 + threadIdx.x;
  if (e < NE) atomicAdd(&cnt[dst[e]], 1);
}

__global__ __launch_bounds__(1024) void k_scan(const int* __restrict__ cnt,
    int* __restrict__ rp, int* __restrict__ cur){
  __shared__ int buf[1024];
  __shared__ int carry;
  int tid = threadIdx.x;
  if (tid==0) carry = 0;
  __syncthreads();
  for (int base=0; base<NN; base+=1024){
    int v = (base+tid < NN) ? cnt[base+tid] : 0;
    buf[tid] = v; __syncthreads();
    for (int off=1; off<1024; off<<=1){
      int t = (tid>=off) ? buf[tid-off] : 0;
      __syncthreads();
      buf[tid] += t;
      __syncthreads();
    }
    int excl = buf[tid] - v + carry;
    if (base+tid < NN){ rp[base+tid] = excl; cur[base+tid] = excl; }
    __syncthreads();
    if (tid==0) carry += buf[1023];
    __syncthreads();
  }
  if (tid==0) rp[NN] = NE;
}

__global__ __launch_bounds__(256) void k_scatter(const int* __restrict__ dst,
    int* __restrict__ cur, int* __restrict__ eidx){
  int e = blockIdx.x*256 + threadIdx.x;
  if (e < NE){ int p = atomicAdd(&cur[dst[e]], 1); eidx[p] = e; }
}

__global__ __launch_bounds__(256) void k_sortrow(const int* __restrict__ rp,
    int* __restrict__ eidx, const int* __restrict__ esrc, const float* __restrict__ ew,
    int* __restrict__ csrc, float* __restrict__ cw){
  int n = blockIdx.x*256 + threadIdx.x;
  if (n >= NN) return;
  int lo = rp[n], hi = rp[n+1];
  for (int a=lo+1; a<hi; a++){
    int k = eidx[a]; int b = a-1;
    while (b>=lo && eidx[b]>k){ eidx[b+1]=eidx[b]; b--; }
    eidx[b+1] = k;
  }
  for (int p=lo; p<hi; p++){ int e = eidx[p]; csrc[p] = esrc[e]; cw[p] = ew[e]; }
}

// Plane layouts (t innermost, 32B per (node,word)):
//   inpb/hs0b/zs0b : [node][w(4)][t(4)]   (NN*16 words)
//   hs1b           : [node][w(8)][t(4)]   (NN*32 words)
//   zs1b           : [node][w(2)][t(4)]   (NN*8  words)

// ---------------- Stage A: inp(t) = poisson(x, k1[t]) ----------------
__global__ __launch_bounds__(256) void k_pois_x(const float* __restrict__ x,
    uint64_t* __restrict__ bits, K8 K){
  int n = blockIdx.x, f = threadIdx.x;
  uint32_t i = (uint32_t)n*256u + (uint32_t)f;
  float xv = x[i];
  uint64_t pack[4];
  #pragma unroll
  for (int t=0;t<4;t++){
    bool b = (u01(jax_bits32(K.a[t],K.b[t], i, TOT)) <= xv);
    pack[t] = __ballot(b);
  }
  if ((f & 63)==0){
    uint64_t* dst = bits + ((size_t)n*4 + (f>>6))*4;
    #pragma unroll
    for (int t=0;t<4;t++) dst[t] = pack[t];
  }
}

// ---------------- Stage B: h0(t) fp32 gather (edge order) + poisson(h0,k2) ----------------
__global__ __launch_bounds__(256) void k_h0(const int* __restrict__ rp,
    const int* __restrict__ csrc, const float* __restrict__ cw,
    const uint64_t* __restrict__ inb, uint64_t* __restrict__ outb, K8 K){
  int n = blockIdx.x, f = threadIdx.x;
  int wi = f>>6, sh = f&63;
  int lo = rp[n], hi = rp[n+1];
  float a[4] = {0.f,0.f,0.f,0.f};
  for (int p=lo;p<hi;p++){
    int s = csrc[p]; float w = cw[p];
    const uint64_t* bp = inb + ((size_t)s*4 + wi)*4;   // 4 t-words, 32B contiguous
    uint64_t w0=bp[0], w1=bp[1], w2=bp[2], w3=bp[3];
    a[0] = __fadd_rn(a[0], ((w0>>sh)&1ull) ? w : 0.0f);
    a[1] = __fadd_rn(a[1], ((w1>>sh)&1ull) ? w : 0.0f);
    a[2] = __fadd_rn(a[2], ((w2>>sh)&1ull) ? w : 0.0f);
    a[3] = __fadd_rn(a[3], ((w3>>sh)&1ull) ? w : 0.0f);
  }
  uint32_t i = (uint32_t)n*256u + (uint32_t)f;
  uint64_t pack[4];
  #pragma unroll
  for (int t=0;t<4;t++){
    bool b = (u01(jax_bits32(K.a[t],K.b[t], i, TOT)) <= a[t]);
    pack[t] = __ballot(b);
  }
  if (sh==0){
    uint64_t* dst = outb + ((size_t)n*4 + wi)*4;
    #pragma unroll
    for (int t=0;t<4;t++) dst[t] = pack[t];
  }
}

// ---------------- Stage C: z0 = LIF_t(hs0 @ W1)  (K=256, M=256) ----------------
// Pure-VALU masked sum: sbfe(1-bit signed) -> and -> fadd. 3 full-rate ops/pair,
// bit-exact vs ascending-k fadd (adding +0.0f is an exact identity here).
__global__ __launch_bounds__(256) void k_z0(const uint64_t* __restrict__ inb,
    const float* __restrict__ W, uint64_t* __restrict__ outb){
  int j = threadIdx.x;
  int n0 = blockIdx.x*4;
  float acc[4][4];                                // [t][i]
  #pragma unroll
  for (int t=0;t<4;t++)
    #pragma unroll
    for (int i=0;i<4;i++) acc[t][i] = 0.0f;

  for (int kw=0;kw<4;kw++){
    uint32_t wlo[4][4], whi[4][4];                // [i][t]
    #pragma unroll
    for (int i=0;i<4;i++){
      const uint64_t* bp = inb + (((size_t)(n0+i))*4 + kw)*4;
      #pragma unroll
      for (int t=0;t<4;t++){
        uint64_t w8 = bp[t];
        wlo[i][t] = (uint32_t)w8;
        whi[i][t] = (uint32_t)(w8>>32);
        FORCE_V(wlo[i][t]); FORCE_V(whi[i][t]);
      }
    }
    const float* Wp = W + (size_t)(kw*64)*256 + j;
    #pragma unroll
    for (int h=0;h<2;h++){
      #pragma unroll
      for (int c=0;c<2;c++){
        float wr[16];
        #pragma unroll
        for (int q=0;q<16;q++) wr[q] = Wp[(size_t)(h*32+c*16+q)*256];
        #pragma unroll
        for (int q=0;q<16;q++){
          int b = c*16+q;
          #pragma unroll
          for (int i=0;i<4;i++){
            #pragma unroll
            for (int t=0;t<4;t++){
              uint32_t wv = h ? whi[i][t] : wlo[i][t];
              acc[t][i] = __fadd_rn(acc[t][i], bitmaskf(wv, b, wr[q]));
            }
          }
        }
      }
    }
  }

  int wi = j>>6;
  #pragma unroll
  for (int i=0;i<4;i++){
    float v = 0.0f;
    uint64_t pack[4];
    #pragma unroll
    for (int t=0;t<4;t++){
      bool s = lif32(v, acc[t][i]);
      pack[t] = __ballot(s);
    }
    if ((j&63)==0){
      uint64_t* dst = outb + (((size_t)(n0+i))*4 + wi)*4;
      #pragma unroll
      for (int t=0;t<4;t++) dst[t] = pack[t];
    }
  }
}

// ---------------- Stage D: h1(t) gather over concat(zs0,hs0), LIF -> hs1 ----------------
__global__ __launch_bounds__(512) void k_h1(const int* __restrict__ rp,
    const int* __restrict__ csrc, const float* __restrict__ cw,
    const uint64_t* __restrict__ zs0b, const uint64_t* __restrict__ hs0b,
    uint64_t* __restrict__ hs1b){
  int n = blockIdx.x, f = threadIdx.x;           // f in [0,512)
  int wi = f>>6, sh = f&63;
  const uint64_t* plane = (wi<4) ? zs0b : hs0b;
  int wo = wi & 3;
  int lo = rp[n], hi = rp[n+1];
  float a[4] = {0.f,0.f,0.f,0.f};
  for (int p=lo;p<hi;p++){
    int s = csrc[p]; float w = cw[p];
    const uint64_t* bp = plane + ((size_t)s*4 + wo)*4;  // 32B contiguous
    uint64_t w0=bp[0], w1=bp[1], w2=bp[2], w3=bp[3];
    a[0] = __fadd_rn(a[0], ((w0>>sh)&1ull) ? w : 0.0f);
    a[1] = __fadd_rn(a[1], ((w1>>sh)&1ull) ? w : 0.0f);
    a[2] = __fadd_rn(a[2], ((w2>>sh)&1ull) ? w : 0.0f);
    a[3] = __fadd_rn(a[3], ((w3>>sh)&1ull) ? w : 0.0f);
  }
  float v = 0.0f;
  uint64_t pack[4];
  #pragma unroll
  for (int t=0;t<4;t++){
    bool s = lif32(v, a[t]);
    pack[t] = __ballot(s);
  }
  if (sh==0){
    uint64_t* dst = hs1b + ((size_t)n*8 + wi)*4;
    #pragma unroll
    for (int t=0;t<4;t++) dst[t] = pack[t];
  }
}

// ---------------- Stage E: z1 = LIF_t(hs1 @ W2)  (K=512, M=128) ----------------
__global__ __launch_bounds__(128) void k_z1(const uint64_t* __restrict__ inb,
    const float* __restrict__ W, uint64_t* __restrict__ outb){
  int j = threadIdx.x;
  int n0 = blockIdx.x*4;
  float acc[4][4];
  #pragma unroll
  for (int t=0;t<4;t++)
    #pragma unroll
    for (int i=0;i<4;i++) acc[t][i] = 0.0f;

  for (int kw=0;kw<8;kw++){
    uint32_t wlo[4][4], whi[4][4];
    #pragma unroll
    for (int i=0;i<4;i++){
      const uint64_t* bp = inb + (((size_t)(n0+i))*8 + kw)*4;
      #pragma unroll
      for (int t=0;t<4;t++){
        uint64_t w8 = bp[t];
        wlo[i][t] = (uint32_t)w8;
        whi[i][t] = (uint32_t)(w8>>32);
        FORCE_V(wlo[i][t]); FORCE_V(whi[i][t]);
      }
    }
    const float* Wp = W + (size_t)(kw*64)*128 + j;
    #pragma unroll
    for (int h=0;h<2;h++){
      #pragma unroll
      for (int c=0;c<2;c++){
        float wr[16];
        #pragma unroll
        for (int q=0;q<16;q++) wr[q] = Wp[(size_t)(h*32+c*16+q)*128];
        #pragma unroll
        for (int q=0;q<16;q++){
          int b = c*16+q;
          #pragma unroll
          for (int i=0;i<4;i++){
            #pragma unroll
            for (int t=0;t<4;t++){
              uint32_t wv = h ? whi[i][t] : wlo[i][t];
              acc[t][i] = __fadd_rn(acc[t][i], bitmaskf(wv, b, wr[q]));
            }
          }
        }
      }
    }
  }

  int wi = j>>6;  // 0 or 1
  #pragma unroll
  for (int i=0;i<4;i++){
    float v = 0.0f;
    uint64_t pack[4];
    #pragma unroll
    for (int t=0;t<4;t++){
      bool s = lif32(v, acc[t][i]);
      pack[t] = __ballot(s);
    }
    if ((j&63)==0){
      uint64_t* dst = outb + (((size_t)(n0+i))*2 + wi)*4;
      #pragma unroll
      for (int t=0;t<4;t++) dst[t] = pack[t];
    }
  }
}

// ---------------- Stage F: decoder + y + sigmoid ----------------
// block = 128 threads: wave0 = row i (ns), wave1 = row i+L (nt); j = DEC column
__global__ __launch_bounds__(128) void k_dec_y(const int* __restrict__ ns,
    const int* __restrict__ nt, const uint64_t* __restrict__ zs1b,
    const float* __restrict__ Wd, const float* __restrict__ bd,
    const float* __restrict__ wrec, float* __restrict__ out){
  int i = blockIdx.x;
  int tid = threadIdx.x;
  int row = tid>>6, j = tid&63;
  int node = row ? nt[i] : ns[i];
  float bdj = bd[j];
  double wrecj = (double)wrec[j];
  __shared__ uint64_t sw[2];

  // load this node's zs1 row: 2 k-groups x 4 t  (64B contiguous)
  uint32_t wlo[2][4], whi[2][4];
  const uint64_t* bp = zs1b + (size_t)node*8;
  #pragma unroll
  for (int g=0;g<2;g++)
    #pragma unroll
    for (int t=0;t<4;t++){
      uint64_t w8 = bp[g*4+t];
      wlo[g][t] = (uint32_t)w8;
      whi[g][t] = (uint32_t)(w8>>32);
      FORCE_V(wlo[g][t]); FORCE_V(whi[g][t]);
    }

  float acc[4] = {0.f,0.f,0.f,0.f};
  #pragma unroll
  for (int g=0;g<2;g++){
    #pragma unroll
    for (int h=0;h<2;h++){
      #pragma unroll
      for (int c=0;c<2;c++){
        float wr[16];
        #pragma unroll
        for (int q=0;q<16;q++) wr[q] = Wd[(size_t)(g*64+h*32+c*16+q)*64 + j];
        #pragma unroll
        for (int q=0;q<16;q++){
          int b = c*16+q;
          #pragma unroll
          for (int t=0;t<4;t++){
            uint32_t wv = h ? whi[g][t] : wlo[g][t];
            acc[t] = __fadd_rn(acc[t], bitmaskf(wv, b, wr[q]));
          }
        }
      }
    }
  }

  float v = 0.0f;
  double ysum = 0.0;
  #pragma unroll
  for (int t=0;t<4;t++){
    float a = __fadd_rn(acc[t], bdj);
    bool s = lif32(v, a);
    uint64_t bw = __ballot(s);
    if (j==0) sw[row] = bw;
    __syncthreads();
    uint64_t m = sw[0] & sw[1];
    __syncthreads();
    double term = ((m>>j)&1ull) ? wrecj : 0.0;
    #pragma unroll
    for (int off=1; off<64; off<<=1) term += shflxor_d(term, off);
    ysum += term;
  }
  if (tid==0) out[i] = (float)(1.0/(1.0 + exp(-0.25*ysum)));
}

// ---------------- Launcher ----------------
extern "C" void kernel_launch(void* const* d_in, const int* in_sizes, int n_in,
                              void* d_out, int out_size, void* d_ws, size_t ws_size,
                              hipStream_t stream) {
  const float* x    = (const float*)d_in[0];
  const float* W1   = (const float*)d_in[1];
  const float* W2   = (const float*)d_in[2];
  const float* Wd   = (const float*)d_in[3];
  const float* bd   = (const float*)d_in[4];
  const float* wrec = (const float*)d_in[5];
  const float* ew   = (const float*)d_in[6];
  const int* esrc   = (const int*)d_in[7];
  const int* edst   = (const int*)d_in[8];
  const int* ns     = (const int*)d_in[9];
  const int* nt     = (const int*)d_in[10];
  float* out = (float*)d_out;
  (void)in_sizes; (void)n_in; (void)out_size; (void)ws_size;

  // workspace layout (~41 MB)
  char* p = (char*)d_ws;
  uint64_t* inpb = (uint64_t*)p; p += (size_t)NN*16*8;
  uint64_t* hs0b = (uint64_t*)p; p += (size_t)NN*16*8;
  uint64_t* zs0b = (uint64_t*)p; p += (size_t)NN*16*8;
  uint64_t* hs1b = (uint64_t*)p; p += (size_t)NN*32*8;
  uint64_t* zs1b = (uint64_t*)p; p += (size_t)NN*8*8;
  int*   eidx = (int*)p;   p += (size_t)NE*4;
  int*   csrc = (int*)p;   p += (size_t)NE*4;
  float* cw   = (float*)p; p += (size_t)NE*4;
  int*   cnt  = (int*)p;   p += (size_t)(NN+2)*4;
  int*   rp   = (int*)p;   p += (size_t)(NN+2)*4;
  int*   cur  = (int*)p;   p += (size_t)(NN+2)*4;

  // host-side key chain: key=(0,42); kt=fold_in(key,t); k1,k2=split(kt)
  K8 K1, K2;
  for (int t=0;t<4;t++){
    uint32_t kt0,kt1;
    tf2x32(0u, 42u, 0u, (uint32_t)t, kt0, kt1);
#if JAX_PARTITIONABLE
    tf2x32(kt0, kt1, 0u, 0u, K1.a[t], K1.b[t]);
    tf2x32(kt0, kt1, 0u, 1u, K2.a[t], K2.b[t]);
#else
    uint32_t A0,B0,A1,B1;
    tf2x32(kt0, kt1, 0u, 2u, A0, B0);
    tf2x32(kt0, kt1, 1u, 3u, A1, B1);
    K1.a[t]=A0; K1.b[t]=A1; K2.a[t]=B0; K2.b[t]=B1;
#endif
  }

  // CSR build (deterministic via per-row sort by edge id)
  hipMemsetAsync(cnt, 0, (size_t)NN*4, stream);
  k_hist   <<<(NE+255)/256, 256, 0, stream>>>(edst, cnt);
  k_scan   <<<1, 1024, 0, stream>>>(cnt, rp, cur);
  k_scatter<<<(NE+255)/256, 256, 0, stream>>>(edst, cur, eidx);
  k_sortrow<<<(NN+255)/256, 256, 0, stream>>>(rp, eidx, esrc, ew, csrc, cw);

  // stage-major pipeline, all T=4 per kernel, LIF state in registers (fp32)
  k_pois_x<<<NN, 256, 0, stream>>>(x, inpb, K1);
  k_h0    <<<NN, 256, 0, stream>>>(rp, csrc, cw, inpb, hs0b, K2);
  k_z0    <<<NN/4, 256, 0, stream>>>(hs0b, W1, zs0b);
  k_h1    <<<NN, 512, 0, stream>>>(rp, csrc, cw, zs0b, hs0b, hs1b);
  k_z1    <<<NN/4, 128, 0, stream>>>(hs1b, W2, zs1b);
  k_dec_y <<<NL, 128, 0, stream>>>(ns, nt, zs1b, Wd, bd, wrec, out);
}